// Round 6
// baseline (140.748 us; speedup 1.0000x reference)
//
#include <hip/hip_runtime.h>

#define Bn 4096
#define Dn 66
#define Hn 512

typedef __attribute__((ext_vector_type(8))) short short8;
typedef __attribute__((ext_vector_type(4))) float f32x4;

__device__ __forceinline__ unsigned short f2bf(float x) {
    union { float f; unsigned u; } v; v.f = x;
    unsigned r = v.u + 0x7fffu + ((v.u >> 16) & 1u);   // RNE
    return (unsigned short)(r >> 16);
}
__device__ __forceinline__ float bf2f(unsigned short h) {
    union { float f; unsigned u; } v; v.u = ((unsigned)h) << 16; return v.f;
}

// Fragment-linear layouts (16x16x32 bf16 MFMA):
//   A-frag tile (rt, ks): lane l holds A[rt*16 + (l&15)][ks*32 + (l>>4)*8 + j]
//       at ((rt*16 + ks)*64 + l)*8 + j        -> 1KB contiguous per wave-load
//   B-frag tile (ct, ks): lane l holds B[ks*32 + (l>>4)*8 + j][ct*16 + (l&15)]
//       at ((ct*16 + ks)*64 + l)*8 + j

// ============ stage 1: h1/s1' (A-frag) + W2P/CmP/W3P fragment packs ============
// bid 0..255  : h1 rows (fp32 K=67 GEMM) -> h1hiP/h1loP/s1P
// bid 256..319: 64x64 W2/M tile -> W2P + CmP (wave-uniform W3 rows, LDS emit)
// bid 320..329: W3P pack (80 tiles, 8 waves/block)
__global__ __launch_bounds__(512, 2) void k_prep(
    const float* __restrict__ xs, const float* __restrict__ tt,
    const float* __restrict__ W1, const float* __restrict__ b1,
    const float* __restrict__ W2, const float* __restrict__ W3,
    unsigned short* __restrict__ W2P, unsigned short* __restrict__ CmP,
    unsigned short* __restrict__ W3P,
    unsigned short* __restrict__ h1hiP, unsigned short* __restrict__ h1loP,
    unsigned short* __restrict__ s1P)
{
    __shared__ float sX[67*16];
    __shared__ float Tw[64*68];
    __shared__ float Mt[64*68];
    const int bid = blockIdx.x, tid = threadIdx.x;
    const int lane = tid & 63, wv = tid >> 6;

    if (bid < 256) {
        const int rt = bid, r0 = rt*16;
        for (int idx = tid; idx < 67*16; idx += 512) {
            const int i = idx >> 4, r = idx & 15;
            sX[idx] = (i < Dn) ? xs[(size_t)(r0+r)*Dn + i] : tt[r0+r];
        }
        __syncthreads();
        const int rg = lane & 7, cg = lane >> 3;
        const int cA = wv*64 + cg*4, cB = cA + 32;
        float z[2][8];
        {
            const float4 bA4 = *(const float4*)&b1[cA];
            const float4 bB4 = *(const float4*)&b1[cB];
            const float bb[8] = {bA4.x,bA4.y,bA4.z,bA4.w, bB4.x,bB4.y,bB4.z,bB4.w};
            #pragma unroll
            for (int j = 0; j < 8; ++j) { z[0][j] = bb[j]; z[1][j] = bb[j]; }
        }
        for (int i = 0; i < 67; ++i) {
            const float2 xf = *(const float2*)&sX[i*16 + 2*rg];
            const float4 wA = *(const float4*)&W1[(size_t)i*Hn + cA];
            const float4 wB = *(const float4*)&W1[(size_t)i*Hn + cB];
            const float ww[8] = {wA.x,wA.y,wA.z,wA.w, wB.x,wB.y,wB.z,wB.w};
            #pragma unroll
            for (int j = 0; j < 8; ++j) {
                z[0][j] = fmaf(xf.x, ww[j], z[0][j]);
                z[1][j] = fmaf(xf.y, ww[j], z[1][j]);
            }
        }
        const int kgrp = cg >> 1, joff = (cg & 1)*4;
        #pragma unroll
        for (int rr = 0; rr < 2; ++rr) {
            const int r = 2*rg + rr;
            #pragma unroll
            for (int grp = 0; grp < 2; ++grp) {
                ushort4 phi, plo, ps;
                unsigned short* PH = (unsigned short*)&phi;
                unsigned short* PL = (unsigned short*)&plo;
                unsigned short* PS = (unsigned short*)&ps;
                #pragma unroll
                for (int j = 0; j < 4; ++j) {
                    const float zv = z[rr][grp*4 + j];
                    const float sg = 1.f / (1.f + __expf(-zv));
                    const float h  = zv * sg;
                    const float sp = sg * (1.f + zv * (1.f - sg));
                    const unsigned short hh = f2bf(h);
                    PH[j] = hh;
                    PL[j] = f2bf(h - bf2f(hh));
                    PS[j] = f2bf(sp);
                }
                const int ks = 2*wv + grp;
                const size_t off = ((size_t)(rt*16 + ks)*64 + r + 16*kgrp)*8 + joff;
                *(ushort4*)&h1hiP[off] = phi;
                *(ushort4*)&h1loP[off] = plo;
                *(ushort4*)&s1P [off] = ps;
            }
        }
    } else if (bid < 320) {
        const int blk = bid - 256;
        const int a0 = (blk >> 3)*64, c0 = (blk & 7)*64;
        // W2 tile -> Tw[c][a] (fp32, transposed); coalesced global reads
        {
            const int a = tid >> 3, cc = (tid & 7)*8;
            const float4 v0 = *(const float4*)&W2[(size_t)(a0+a)*Hn + c0 + cc];
            const float4 v1 = *(const float4*)&W2[(size_t)(a0+a)*Hn + c0 + cc + 4];
            Tw[(cc+0)*68 + a] = v0.x; Tw[(cc+1)*68 + a] = v0.y;
            Tw[(cc+2)*68 + a] = v0.z; Tw[(cc+3)*68 + a] = v0.w;
            Tw[(cc+4)*68 + a] = v1.x; Tw[(cc+5)*68 + a] = v1.y;
            Tw[(cc+6)*68 + a] = v1.z; Tw[(cc+7)*68 + a] = v1.w;
        }
        // M[c][a] = sum_i W3[c,i]*W1[i,a]; wave-uniform c -> W3 scalarizes
        {
            const int cl0 = wv*8;
            #pragma unroll 2
            for (int cl = 0; cl < 8; ++cl) {
                const int c = c0 + cl0 + cl;
                float m = 0.f;
                for (int i = 0; i < Dn; ++i)
                    m = fmaf(W3[(size_t)c*Dn + i], W1[(size_t)i*Hn + a0 + lane], m);
                Mt[(cl0+cl)*68 + lane] = m;
            }
        }
        __syncthreads();
        // emit one B-frag tile per wave
        const int ctl = wv & 3, ksl = wv >> 2;
        const int n = lane & 15, kg = lane >> 4;
        const int cL = ctl*16 + n, aL = ksl*32 + kg*8;
        const float4 wlo = *(const float4*)&Tw[cL*68 + aL];
        const float4 whi = *(const float4*)&Tw[cL*68 + aL + 4];
        const float4 mlo = *(const float4*)&Mt[cL*68 + aL];
        const float4 mhi = *(const float4*)&Mt[cL*68 + aL + 4];
        const float wv8[8] = {wlo.x,wlo.y,wlo.z,wlo.w, whi.x,whi.y,whi.z,whi.w};
        const float mv8[8] = {mlo.x,mlo.y,mlo.z,mlo.w, mhi.x,mhi.y,mhi.z,mhi.w};
        short8 pw, pc;
        #pragma unroll
        for (int j = 0; j < 8; ++j) {
            pw[j] = (short)f2bf(wv8[j]);
            pc[j] = (short)f2bf(wv8[j] * mv8[j]);
        }
        const int tix = ((blk & 7)*4 + ctl)*16 + ((blk >> 3)*2 + ksl);
        const size_t off = ((size_t)tix*64 + lane)*8;
        *(short8*)&W2P[off] = pw;
        *(short8*)&CmP[off] = pc;
    } else {
        const int tix = (bid - 320)*8 + wv;   // jt*16 + ks, 80 tiles
        const int ks = tix & 15;
        const int n = lane & 15, kg = lane >> 4;
        const int j_out = (tix >> 4)*16 + n;
        const int abase = ks*32 + kg*8;
        short8 p;
        #pragma unroll
        for (int j = 0; j < 8; ++j)
            p[j] = (j_out < Dn) ? (short)f2bf(W3[(size_t)(abase + j)*Dn + j_out]) : (short)0;
        *(short8*)&W3P[((size_t)tix*64 + lane)*8] = p;
    }
}

// ============ stage 2: z2/v GEMM, 32 rows x 128 cols per block ============
// grid 512 = 128 row-pairs x 4 col-quarters; 4 waves x (2 rt x 2 ct) tiles.
__global__ __launch_bounds__(256, 2) void k_gemm2(
    const unsigned short* __restrict__ h1hiP, const unsigned short* __restrict__ h1loP,
    const unsigned short* __restrict__ s1P,
    const unsigned short* __restrict__ W2P, const unsigned short* __restrict__ CmP,
    const float* __restrict__ b2,
    unsigned short* __restrict__ h2hiP, unsigned short* __restrict__ h2loP,
    float* __restrict__ dpPart)
{
    __shared__ float sRed[4*32];
    const int tid = threadIdx.x, lane = tid & 63, wv = tid >> 6;
    const int brt = blockIdx.x >> 2, cq = blockIdx.x & 3;
    const int rt0 = brt*2;
    const int ctb = cq*8 + wv*2;             // 2 ctiles per wave
    const int n = lane & 15, kg = lane >> 4;

    f32x4 zac[2][2], vac[2][2];
    #pragma unroll
    for (int ti = 0; ti < 2; ++ti) {
        const float bz = b2[(ctb + ti)*16 + n];
        #pragma unroll
        for (int rr = 0; rr < 2; ++rr) {
            zac[rr][ti] = (f32x4){bz, bz, bz, bz};
            vac[rr][ti] = (f32x4){0.f, 0.f, 0.f, 0.f};
        }
    }
    #pragma unroll 2
    for (int ks = 0; ks < 16; ++ks) {
        const size_t a0 = ((size_t)(rt0*16 + ks)*64 + lane)*8;
        const size_t a1 = ((size_t)((rt0+1)*16 + ks)*64 + lane)*8;
        const short8 ahi0 = *(const short8*)&h1hiP[a0];
        const short8 alo0 = *(const short8*)&h1loP[a0];
        const short8 as0  = *(const short8*)&s1P [a0];
        const short8 ahi1 = *(const short8*)&h1hiP[a1];
        const short8 alo1 = *(const short8*)&h1loP[a1];
        const short8 as1  = *(const short8*)&s1P [a1];
        #pragma unroll
        for (int ti = 0; ti < 2; ++ti) {
            const size_t wo = ((size_t)((ctb + ti)*16 + ks)*64 + lane)*8;
            const short8 wf = *(const short8*)&W2P[wo];
            const short8 qf = *(const short8*)&CmP[wo];
            zac[0][ti] = __builtin_amdgcn_mfma_f32_16x16x32_bf16(ahi0, wf, zac[0][ti], 0, 0, 0);
            zac[0][ti] = __builtin_amdgcn_mfma_f32_16x16x32_bf16(alo0, wf, zac[0][ti], 0, 0, 0);
            vac[0][ti] = __builtin_amdgcn_mfma_f32_16x16x32_bf16(as0,  qf, vac[0][ti], 0, 0, 0);
            zac[1][ti] = __builtin_amdgcn_mfma_f32_16x16x32_bf16(ahi1, wf, zac[1][ti], 0, 0, 0);
            zac[1][ti] = __builtin_amdgcn_mfma_f32_16x16x32_bf16(alo1, wf, zac[1][ti], 0, 0, 0);
            vac[1][ti] = __builtin_amdgcn_mfma_f32_16x16x32_bf16(as1,  qf, vac[1][ti], 0, 0, 0);
        }
    }
    float dp[2][4] = {{0.f,0.f,0.f,0.f},{0.f,0.f,0.f,0.f}};
    #pragma unroll
    for (int rr = 0; rr < 2; ++rr) {
        const int rt = rt0 + rr;
        #pragma unroll
        for (int ti = 0; ti < 2; ++ti) {
            const int c = (ctb + ti)*16 + n;
            const int ks2 = c >> 5, kg2 = (c >> 3) & 3, j2 = c & 7;
            #pragma unroll
            for (int q = 0; q < 4; ++q) {
                const float z2 = zac[rr][ti][q];
                const float sg = 1.f / (1.f + __expf(-z2));
                const float h2 = z2 * sg;
                dp[rr][q] = fmaf(sg * (1.f + z2 * (1.f - sg)), vac[rr][ti][q], dp[rr][q]);
                const unsigned short hh = f2bf(h2);
                const size_t o = ((size_t)(rt*16 + ks2)*64 + (kg*4 + q) + 16*kg2)*8 + j2;
                h2hiP[o] = hh;
                h2loP[o] = f2bf(h2 - bf2f(hh));
            }
        }
    }
    #pragma unroll
    for (int rr = 0; rr < 2; ++rr) {
        #pragma unroll
        for (int q = 0; q < 4; ++q) {
            float v = dp[rr][q];
            v += __shfl_xor(v, 1, 64);
            v += __shfl_xor(v, 2, 64);
            v += __shfl_xor(v, 4, 64);
            v += __shfl_xor(v, 8, 64);
            if (n == 0) sRed[wv*32 + rr*16 + kg*4 + q] = v;
        }
    }
    __syncthreads();
    if (tid < 32) {
        const float s = sRed[tid] + sRed[32+tid] + sRed[64+tid] + sRed[96+tid];
        dpPart[(size_t)cq*Bn + rt0*16 + tid] = s;
    }
}

// ============ stage 3: out = h2@W3 + b3 (hi/lo) + divergence finalize ============
__global__ __launch_bounds__(64, 2) void k_gemm3(
    const unsigned short* __restrict__ h2hiP, const unsigned short* __restrict__ h2loP,
    const unsigned short* __restrict__ W3P, const float* __restrict__ b3,
    const float* __restrict__ dpPart, float* __restrict__ out)
{
    const int lane = threadIdx.x;
    const int rt = blockIdx.x / 5, jt = blockIdx.x % 5;
    const int r0 = rt*16;
    const int n = lane & 15, kg = lane >> 4;
    const int j = jt*16 + n;
    const float bj = (j < Dn) ? b3[j] : 0.f;
    f32x4 oac = (f32x4){bj, bj, bj, bj};
    #pragma unroll 4
    for (int ks = 0; ks < 16; ++ks) {
        const size_t aoff = ((size_t)(rt*16 + ks)*64 + lane)*8;
        const short8 ahi = *(const short8*)&h2hiP[aoff];
        const short8 alo = *(const short8*)&h2loP[aoff];
        const short8 wf  = *(const short8*)&W3P[((size_t)(jt*16 + ks)*64 + lane)*8];
        oac = __builtin_amdgcn_mfma_f32_16x16x32_bf16(ahi, wf, oac, 0, 0, 0);
        oac = __builtin_amdgcn_mfma_f32_16x16x32_bf16(alo, wf, oac, 0, 0, 0);
    }
    if (j < Dn) {
        #pragma unroll
        for (int q = 0; q < 4; ++q)
            out[(size_t)(r0 + kg*4 + q)*Dn + j] = oac[q];
    }
    if (jt == 0 && lane < 16) {
        const int r = r0 + lane;
        out[(size_t)Bn*Dn + r] = -(dpPart[r] + dpPart[Bn + r] + dpPart[2*Bn + r] + dpPart[3*Bn + r]);
    }
}

extern "C" void kernel_launch(void* const* d_in, const int* in_sizes, int n_in,
                              void* d_out, int out_size, void* d_ws, size_t ws_size,
                              hipStream_t stream)
{
    const float* xs = (const float*)d_in[0];
    const float* t  = (const float*)d_in[1];
    const float* W1 = (const float*)d_in[2];
    const float* b1 = (const float*)d_in[3];
    const float* W2 = (const float*)d_in[4];
    const float* b2 = (const float*)d_in[5];
    const float* W3 = (const float*)d_in[6];
    const float* b3 = (const float*)d_in[7];
    float* out = (float*)d_out;

    char* ws = (char*)d_ws;
    unsigned short* W2P  = (unsigned short*)(ws);                    // 512 KB
    unsigned short* CmP  = (unsigned short*)(ws + 524288);           // 512 KB
    unsigned short* W3P  = (unsigned short*)(ws + 1048576);          // 80 KB
    unsigned short* h1hi = (unsigned short*)(ws + 1130496);          // 4 MB
    unsigned short* h1lo = (unsigned short*)(ws + 5324800);          // 4 MB
    unsigned short* s1   = (unsigned short*)(ws + 9519104);          // 4 MB
    unsigned short* h2hi = (unsigned short*)(ws + 13713408);         // 4 MB
    unsigned short* h2lo = (unsigned short*)(ws + 17907712);         // 4 MB
    float*          dpP  = (float*)(ws + 22102016);                  // 64 KB

    k_prep <<<330, 512, 0, stream>>>(xs, t, W1, b1, W2, W3, W2P, CmP, W3P, h1hi, h1lo, s1);
    k_gemm2<<<512, 256, 0, stream>>>(h1hi, h1lo, s1, W2P, CmP, b2, h2hi, h2lo, dpP);
    k_gemm3<<<1280, 64, 0, stream>>>(h2hi, h2lo, W3P, b3, dpP, out);
}

// Round 7
// 118.484 us; speedup vs baseline: 1.1879x; 1.1879x over previous
//
#include <hip/hip_runtime.h>

#define Bn 4096
#define Dn 66
#define Hn 512

typedef __attribute__((ext_vector_type(8))) short short8;
typedef __attribute__((ext_vector_type(4))) float f32x4;

__device__ __forceinline__ unsigned short f2bf(float x) {
    union { float f; unsigned u; } v; v.f = x;
    unsigned r = v.u + 0x7fffu + ((v.u >> 16) & 1u);   // RNE
    return (unsigned short)(r >> 16);
}
__device__ __forceinline__ float bf2f(unsigned short h) {
    union { float f; unsigned u; } v; v.u = ((unsigned)h) << 16; return v.f;
}

// Fragment-linear layouts (16x16x32 bf16 MFMA):
//   A-frag tile (rt, ks): lane l holds A[rt*16 + (l&15)][ks*32 + (l>>4)*8 + j]
//       at ((rt*16 + ks)*64 + l)*8 + j        -> 1KB contiguous per wave-load
//   B-frag tile (ct, ks): lane l holds B[ks*32 + (l>>4)*8 + j][ct*16 + (l&15)]
//       at ((ct*16 + ks)*64 + l)*8 + j

// ============ stage 1 (R5 verbatim): h1/s1' (A-frag) + W2P/CmP/W3P packs ============
__global__ __launch_bounds__(512, 2) void k_prep(
    const float* __restrict__ xs, const float* __restrict__ tt,
    const float* __restrict__ W1, const float* __restrict__ b1,
    const float* __restrict__ W2, const float* __restrict__ W3,
    unsigned short* __restrict__ W2P, unsigned short* __restrict__ CmP,
    unsigned short* __restrict__ W3P,
    unsigned short* __restrict__ h1hiP, unsigned short* __restrict__ h1loP,
    unsigned short* __restrict__ s1P)
{
    __shared__ float sX[67*16];
    const int bid = blockIdx.x, tid = threadIdx.x;
    const int lane = tid & 63, wv = tid >> 6;

    if (bid < 256) {
        const int rt = bid, r0 = rt*16;
        for (int idx = tid; idx < 67*16; idx += 512) {
            const int i = idx >> 4, r = idx & 15;
            sX[idx] = (i < Dn) ? xs[(size_t)(r0+r)*Dn + i] : tt[r0+r];
        }
        __syncthreads();
        const int rg = lane & 7, cg = lane >> 3;
        const int cA = wv*64 + cg*4, cB = cA + 32;
        float z[2][8];
        {
            const float4 bA4 = *(const float4*)&b1[cA];
            const float4 bB4 = *(const float4*)&b1[cB];
            const float bb[8] = {bA4.x,bA4.y,bA4.z,bA4.w, bB4.x,bB4.y,bB4.z,bB4.w};
            #pragma unroll
            for (int j = 0; j < 8; ++j) { z[0][j] = bb[j]; z[1][j] = bb[j]; }
        }
        for (int i = 0; i < 67; ++i) {
            const float2 xf = *(const float2*)&sX[i*16 + 2*rg];
            const float4 wA = *(const float4*)&W1[(size_t)i*Hn + cA];
            const float4 wB = *(const float4*)&W1[(size_t)i*Hn + cB];
            const float ww[8] = {wA.x,wA.y,wA.z,wA.w, wB.x,wB.y,wB.z,wB.w};
            #pragma unroll
            for (int j = 0; j < 8; ++j) {
                z[0][j] = fmaf(xf.x, ww[j], z[0][j]);
                z[1][j] = fmaf(xf.y, ww[j], z[1][j]);
            }
        }
        const int kgrp = cg >> 1, joff = (cg & 1)*4;
        #pragma unroll
        for (int rr = 0; rr < 2; ++rr) {
            const int r = 2*rg + rr;
            #pragma unroll
            for (int grp = 0; grp < 2; ++grp) {
                ushort4 phi, plo, ps;
                unsigned short* PH = (unsigned short*)&phi;
                unsigned short* PL = (unsigned short*)&plo;
                unsigned short* PS = (unsigned short*)&ps;
                #pragma unroll
                for (int j = 0; j < 4; ++j) {
                    const float zv = z[rr][grp*4 + j];
                    const float sg = 1.f / (1.f + __expf(-zv));
                    const float h  = zv * sg;
                    const float sp = sg * (1.f + zv * (1.f - sg));
                    const unsigned short hh = f2bf(h);
                    PH[j] = hh;
                    PL[j] = f2bf(h - bf2f(hh));
                    PS[j] = f2bf(sp);
                }
                const int ks = 2*wv + grp;
                const size_t off = ((size_t)(rt*16 + ks)*64 + r + 16*kgrp)*8 + joff;
                *(ushort4*)&h1hiP[off] = phi;
                *(ushort4*)&h1loP[off] = plo;
                *(ushort4*)&s1P [off] = ps;
            }
        }
    } else if (bid < 320) {
        // one B-frag tile per wave: tix = ct*16 + ks
        const int tix = (bid - 256)*8 + wv;
        const int ks = tix & 15;
        const int n = lane & 15, kg = lane >> 4;
        const int c = (tix >> 4)*16 + n;
        const int abase = ks*32 + kg*8;
        float w2v[8], m[8];
        #pragma unroll
        for (int j = 0; j < 8; ++j) {
            w2v[j] = W2[(size_t)(abase + j)*Hn + c];
            m[j] = 0.f;
        }
        for (int i = 0; i < Dn; ++i) {
            const float w3 = W3[(size_t)c*Dn + i];
            const float4 w1a = *(const float4*)&W1[(size_t)i*Hn + abase];
            const float4 w1b = *(const float4*)&W1[(size_t)i*Hn + abase + 4];
            m[0] = fmaf(w3, w1a.x, m[0]); m[1] = fmaf(w3, w1a.y, m[1]);
            m[2] = fmaf(w3, w1a.z, m[2]); m[3] = fmaf(w3, w1a.w, m[3]);
            m[4] = fmaf(w3, w1b.x, m[4]); m[5] = fmaf(w3, w1b.y, m[5]);
            m[6] = fmaf(w3, w1b.z, m[6]); m[7] = fmaf(w3, w1b.w, m[7]);
        }
        short8 pw, pc;
        #pragma unroll
        for (int j = 0; j < 8; ++j) {
            pw[j] = (short)f2bf(w2v[j]);
            pc[j] = (short)f2bf(w2v[j] * m[j]);
        }
        const size_t off = ((size_t)tix*64 + lane)*8;
        *(short8*)&W2P[off] = pw;
        *(short8*)&CmP[off] = pc;
    } else {
        const int tix = (bid - 320)*8 + wv;   // jt*16 + ks, 80 tiles
        if (tix < 80) {
            const int ks = tix & 15;
            const int n = lane & 15, kg = lane >> 4;
            const int j_out = (tix >> 4)*16 + n;
            const int abase = ks*32 + kg*8;
            short8 p;
            #pragma unroll
            for (int j = 0; j < 8; ++j)
                p[j] = (j_out < Dn) ? (short)f2bf(W3[(size_t)(abase + j)*Dn + j_out]) : (short)0;
            *(short8*)&W3P[((size_t)tix*64 + lane)*8] = p;
        }
    }
}

// ============ stage 2+3 fused: z2/v GEMM -> h2 in LDS -> out GEMM + divergence ============
// grid 256: one 16-row tile per block; 8 waves x 64 cols (full H). All global loads
// are 1KB contiguous per wave. h2 hi/lo staged in LDS A-frag layout (no global trip).
__global__ __launch_bounds__(512, 2) void k_fuse23(
    const unsigned short* __restrict__ h1hiP, const unsigned short* __restrict__ h1loP,
    const unsigned short* __restrict__ s1P,
    const unsigned short* __restrict__ W2P, const unsigned short* __restrict__ CmP,
    const float* __restrict__ b2,
    const unsigned short* __restrict__ W3P, const float* __restrict__ b3,
    float* __restrict__ out)
{
    __shared__ __align__(16) unsigned short sH[16*Hn];   // h2 hi, A-frag layout (16 KB)
    __shared__ __align__(16) unsigned short sL[16*Hn];   // h2 lo (16 KB)
    __shared__ float sRed[8*16];
    const int tid = threadIdx.x, lane = tid & 63, wv = tid >> 6;
    const int rt = blockIdx.x;
    const int r0 = rt*16;
    const int ctb = wv*4;                    // 4 ctiles per wave -> cols [wv*64, wv*64+64)
    const int n = lane & 15, kg = lane >> 4;

    // ---- phase B: z2 = h1@W2 + b2, v = s1'@Cmat ----
    f32x4 zac[4], vac[4];
    #pragma unroll
    for (int ti = 0; ti < 4; ++ti) {
        const float bz = b2[(ctb + ti)*16 + n];
        zac[ti] = (f32x4){bz, bz, bz, bz};
        vac[ti] = (f32x4){0.f, 0.f, 0.f, 0.f};
    }
    #pragma unroll 2
    for (int ks = 0; ks < 16; ++ks) {
        const size_t aoff = ((size_t)(rt*16 + ks)*64 + lane)*8;
        const short8 ahi = *(const short8*)&h1hiP[aoff];
        const short8 alo = *(const short8*)&h1loP[aoff];
        const short8 as1 = *(const short8*)&s1P [aoff];
        #pragma unroll
        for (int ti = 0; ti < 4; ++ti) {
            const size_t wo = ((size_t)((ctb + ti)*16 + ks)*64 + lane)*8;
            const short8 wf = *(const short8*)&W2P[wo];
            const short8 qf = *(const short8*)&CmP[wo];
            zac[ti] = __builtin_amdgcn_mfma_f32_16x16x32_bf16(ahi, wf, zac[ti], 0, 0, 0);
            zac[ti] = __builtin_amdgcn_mfma_f32_16x16x32_bf16(alo, wf, zac[ti], 0, 0, 0);
            vac[ti] = __builtin_amdgcn_mfma_f32_16x16x32_bf16(as1, qf, vac[ti], 0, 0, 0);
        }
    }

    // ---- epilogue: silu -> h2 hi/lo into LDS (A-frag), divergence partials ----
    float dp[4] = {0.f, 0.f, 0.f, 0.f};
    #pragma unroll
    for (int ti = 0; ti < 4; ++ti) {
        const int c = (ctb + ti)*16 + n;
        const int ks2 = c >> 5, kg2 = (c >> 3) & 3, j2 = c & 7;
        #pragma unroll
        for (int q = 0; q < 4; ++q) {
            const float z2 = zac[ti][q];
            const float sg = 1.f / (1.f + __expf(-z2));
            const float h2 = z2 * sg;
            dp[q] = fmaf(sg * (1.f + z2 * (1.f - sg)), vac[ti][q], dp[q]);
            const unsigned short hh = f2bf(h2);
            const int o = (ks2*64 + (kg*4 + q) + 16*kg2)*8 + j2;
            sH[o] = hh;
            sL[o] = f2bf(h2 - bf2f(hh));
        }
    }
    #pragma unroll
    for (int q = 0; q < 4; ++q) {
        float v = dp[q];
        v += __shfl_xor(v, 1, 64);
        v += __shfl_xor(v, 2, 64);
        v += __shfl_xor(v, 4, 64);
        v += __shfl_xor(v, 8, 64);
        if (n == 0) sRed[wv*16 + kg*4 + q] = v;
    }
    __syncthreads();

    // ---- divergence finalize (local to block) ----
    if (tid < 16) {
        float s = 0.f;
        #pragma unroll
        for (int q = 0; q < 8; ++q) s += sRed[q*16 + tid];
        out[(size_t)Bn*Dn + r0 + tid] = -s;
    }

    // ---- phase C: out = h2 @ W3 + b3 (waves 0..4, one 16-col j-tile each) ----
    if (wv < 5) {
        const int jt = wv;
        const int j = jt*16 + n;
        const float bj = (j < Dn) ? b3[j] : 0.f;
        f32x4 oac = (f32x4){bj, bj, bj, bj};
        #pragma unroll 4
        for (int ks = 0; ks < 16; ++ks) {
            const int aoff = (ks*64 + lane)*8;
            const short8 ahi = *(const short8*)&sH[aoff];
            const short8 alo = *(const short8*)&sL[aoff];
            const short8 wf  = *(const short8*)&W3P[((size_t)(jt*16 + ks)*64 + lane)*8];
            oac = __builtin_amdgcn_mfma_f32_16x16x32_bf16(ahi, wf, oac, 0, 0, 0);
            oac = __builtin_amdgcn_mfma_f32_16x16x32_bf16(alo, wf, oac, 0, 0, 0);
        }
        if (j < Dn) {
            #pragma unroll
            for (int q = 0; q < 4; ++q)
                out[(size_t)(r0 + kg*4 + q)*Dn + j] = oac[q];
        }
    }
}

extern "C" void kernel_launch(void* const* d_in, const int* in_sizes, int n_in,
                              void* d_out, int out_size, void* d_ws, size_t ws_size,
                              hipStream_t stream)
{
    const float* xs = (const float*)d_in[0];
    const float* t  = (const float*)d_in[1];
    const float* W1 = (const float*)d_in[2];
    const float* b1 = (const float*)d_in[3];
    const float* W2 = (const float*)d_in[4];
    const float* b2 = (const float*)d_in[5];
    const float* W3 = (const float*)d_in[6];
    const float* b3 = (const float*)d_in[7];
    float* out = (float*)d_out;

    char* ws = (char*)d_ws;
    unsigned short* W2P  = (unsigned short*)(ws);                    // 512 KB
    unsigned short* CmP  = (unsigned short*)(ws + 524288);           // 512 KB
    unsigned short* W3P  = (unsigned short*)(ws + 1048576);          // 80 KB
    unsigned short* h1hi = (unsigned short*)(ws + 1130496);          // 4 MB
    unsigned short* h1lo = (unsigned short*)(ws + 5324800);          // 4 MB
    unsigned short* s1   = (unsigned short*)(ws + 9519104);          // 4 MB

    k_prep  <<<330, 512, 0, stream>>>(xs, t, W1, b1, W2, W3, W2P, CmP, W3P, h1hi, h1lo, s1);
    k_fuse23<<<256, 512, 0, stream>>>(h1hi, h1lo, s1, W2P, CmP, b2, W3P, b3, out);
}